// Round 8
// baseline (190.153 us; speedup 1.0000x reference)
//
#include <hip/hip_runtime.h>

// GraphAugmentation fused kernel, MI355X — R8.
//
// Algebra (unchanged):
//  * softmax over 8 identical affinities == 1/8 -> Q/K/attn dead.
//  * u = [xc ; xavg] (K=32), xavg = mean of 8 rolls of x.
//  * agg    = [0|mw] @ u + mb
//  * hidden = relu(W1' @ u + b1'), W1' = [g1w_x | g1w_a@mw] (rows permuted
//             so hidden MFMA D-regs ARE the gate B-fragment — R7-proven)
//  * gate   = sigmoid(g2w @ hidden + g2b);  out = agg * gate
//
// R8 vs R7 (88us, latency-bound: 144 scalar gather loads/thread at VGPR=52):
//  * thread owns pixel pair (w, w+1): ALL taps become dwordx2 (cols are
//    consecutive for any dx). Wrap-at-511 handled by a rare whole-wave
//    scalar path (__any). 2x fewer load instructions -> 2x deeper pipeline.
//  * 128-thr blocks (2 waves), 22.7KB LDS -> 7 blocks/CU = 14 waves/CU.
//  * no VGPR cap; u held in 8 half8 regs, written as 8 ds_write_b128
//    (stride-40 layout: bank-uniform at the 8-cycle floor).

#define HW 262144   // 512*512
#define WD 512

typedef _Float16 half8 __attribute__((ext_vector_type(8)));
typedef float    f32x4 __attribute__((ext_vector_type(4)));

#define MFMA16(A, B, C) __builtin_amdgcn_mfma_f32_16x16x32_f16((A), (B), (C), 0, 0, 0)

__global__ __launch_bounds__(128) void ga_main(
    const float* __restrict__ x,
    const float* __restrict__ mw,  const float* __restrict__ mb,
    const float* __restrict__ g1w, const float* __restrict__ g1b,
    const float* __restrict__ g2w, const float* __restrict__ g2b,
    float* __restrict__ out)
{
  constexpr int DY[8] = {-4, -4, -4, -3, -2, 2, 3, 4};
  constexpr int DX[8] = {-4, -1,  2,  4, -3, 3, -2, 4};

  __shared__ _Float16 u_s[2][128 * 40];  // 20 KB: per-wave u staging (stride 40)
  __shared__ float    w1a[32 * 16];      //  2 KB: W1' columns k>=16
  __shared__ float    b1s[32];           // b1' = g1b + g1w_a @ mb

  const int tid  = threadIdx.x;          // 0..127
  const int wv   = tid >> 6, lane = tid & 63;
  const int q    = lane >> 4, m = lane & 15;

  // ---- block-cooperative prep: W1'a[j][c] and b1'[j] into LDS ----
  for (int idx = tid; idx < 512; idx += 128) {
    const int j = idx >> 4, c = idx & 15;
    float s = 0.f;
#pragma unroll
    for (int t2 = 0; t2 < 16; ++t2)
      s += g1w[j * 32 + 16 + t2] * mw[t2 * 16 + c];
    w1a[idx] = s;
  }
  if (tid < 32) {
    float s = g1b[tid];
#pragma unroll
    for (int t2 = 0; t2 < 16; ++t2)
      s += g1w[tid * 32 + 16 + t2] * mb[t2];
    b1s[tid] = s;
  }
  __syncthreads();

  // ---- per-lane weight A-fragments (fp16 hi+lo); hidden rows permuted ----
  const int j0 = 8 * (m >> 2) + (m & 3);
  const int j1 = j0 + 4;
  half8 aAg_h, aAg_l, aH0_h, aH0_l, aH1_h, aH1_l, aG2_h, aG2_l;
#pragma unroll
  for (int e = 0; e < 8; ++e) {
    const int kk = 8 * q + e;
    float v0 = 0.f;
    if (kk >= 16) v0 = mw[m * 16 + (kk - 16)];      // Abar = [0 | mw]
    _Float16 h = (_Float16)v0;
    aAg_h[e] = h; aAg_l[e] = (_Float16)(v0 - (float)h);

    float v1, v2;
    if (kk < 16) { v1 = g1w[j0 * 32 + kk];        v2 = g1w[j1 * 32 + kk]; }
    else         { v1 = w1a[j0 * 16 + (kk - 16)]; v2 = w1a[j1 * 16 + (kk - 16)]; }
    h = (_Float16)v1; aH0_h[e] = h; aH0_l[e] = (_Float16)(v1 - (float)h);
    h = (_Float16)v2; aH1_h[e] = h; aH1_l[e] = (_Float16)(v2 - (float)h);

    const float v3 = g2w[m * 32 + kk];
    h = (_Float16)v3; aG2_h[e] = h; aG2_l[e] = (_Float16)(v3 - (float)h);
  }
  f32x4 bias0, bias1, bias2, bias3;
#pragma unroll
  for (int rg = 0; rg < 4; ++rg) {
    bias0[rg] = mb[4 * q + rg];
    bias1[rg] = b1s[8 * q + rg];        // acc_h0 reg rg = h-ch 8q+rg
    bias2[rg] = b1s[8 * q + 4 + rg];    // acc_h1 reg rg = h-ch 8q+4+rg
    bias3[rg] = g2b[4 * q + rg];
  }

  // ---- XCD-aware bijective swizzle: 4096 wgs, chunk 512 ----
  const int swz = ((blockIdx.x & 7) << 9) | (blockIdx.x >> 3);
  const int b   = swz >> 10;
  const int rem = swz & 1023;
  const int row = rem >> 1;
  const int wavecol = ((rem & 1) << 8) + (wv << 7);  // this wave's 128-col span
  const int w0  = wavecol + (lane << 1);             // thread's pixel pair (w0, w0+1)

  const float* xb = x + b * 16 * HW;

  // ---- tap element-offsets for the pixel pair ----
  unsigned idxA[8], idxB[8];
  bool lsplit = false;
#pragma unroll
  for (int i = 0; i < 8; ++i) {
    const unsigned ro = ((row - DY[i]) & 511) * WD;
    const int baseA = (w0 - DX[i]) & 511;
    idxA[i] = ro + baseA;
    idxB[i] = ro + ((w0 + 1 - DX[i]) & 511);
    if (baseA == 511) lsplit = true;   // pair would cross the wrap boundary
  }
  const bool wsplit = __any(lsplit);   // wave-uniform slow-path flag (rare)
  const unsigned ctr = row * WD + w0;

  // ---- gathers: center pair + 8 tap pairs per channel; pack u to fp16 ----
  half8 uc0lo, uc0hi, ua0lo, ua0hi, uc1lo, uc1hi, ua1lo, ua1hi;
#pragma unroll
  for (int c = 0; c < 16; ++c) {
    const float* xp = xb + c * HW;
    const float2 cv = *(const float2*)(xp + ctr);
    float s0 = 0.f, s1 = 0.f;
    if (!wsplit) {
#pragma unroll
      for (int i = 0; i < 8; ++i) {
        const float2 v = *(const float2*)(xp + idxA[i]);   // dwordx2 tap
        s0 += v.x; s1 += v.y;
      }
    } else {
#pragma unroll
      for (int i = 0; i < 8; ++i) { s0 += xp[idxA[i]]; s1 += xp[idxB[i]]; }
    }
    const _Float16 hc0 = (_Float16)cv.x;
    const _Float16 hc1 = (_Float16)cv.y;
    const _Float16 ha0 = (_Float16)(s0 * 0.125f);
    const _Float16 ha1 = (_Float16)(s1 * 0.125f);
    if (c < 8) { uc0lo[c] = hc0; uc1lo[c] = hc1; ua0lo[c] = ha0; ua1lo[c] = ha1; }
    else { uc0hi[c - 8] = hc0; uc1hi[c - 8] = hc1; ua0hi[c - 8] = ha0; ua1hi[c - 8] = ha1; }
  }

  // ---- stage u for both pixels: 8 x ds_write_b128, stride-40 layout ----
  _Float16* u0 = &u_s[wv][(lane << 1) * 40];
  _Float16* u1 = u0 + 40;
  *(half8*)(u0 +  0) = uc0lo;  *(half8*)(u0 +  8) = uc0hi;
  *(half8*)(u0 + 16) = ua0lo;  *(half8*)(u0 + 24) = ua0hi;
  *(half8*)(u1 +  0) = uc1lo;  *(half8*)(u1 +  8) = uc1hi;
  *(half8*)(u1 + 16) = ua1lo;  *(half8*)(u1 + 24) = ua1hi;

  // ---- 8 groups of 16 px: MFMA + epilogue (wave-private, no syncthreads) ----
  const _Float16* ubase = u_s[wv];
  float* ob = out + b * 16 * HW + row * WD + wavecol;
  const f32x4 z = {0.f, 0.f, 0.f, 0.f};

#pragma unroll
  for (int g = 0; g < 8; ++g) {
    const half8 bf = *(const half8*)(ubase + (g * 16 + m) * 40 + q * 8);

    f32x4 acc_a  = MFMA16(aAg_l, bf, z);
    acc_a        = MFMA16(aAg_h, bf, acc_a);
    f32x4 acc_h0 = MFMA16(aH0_l, bf, z);
    acc_h0       = MFMA16(aH0_h, bf, acc_h0);
    f32x4 acc_h1 = MFMA16(aH1_l, bf, z);
    acc_h1       = MFMA16(aH1_h, bf, acc_h1);

    // relu + fp16 pack: registers ARE the gate B-fragment (row-permuted W1')
    half8 gB;
#pragma unroll
    for (int rg = 0; rg < 4; ++rg) {
      gB[rg]     = (_Float16)fmaxf(acc_h0[rg] + bias1[rg], 0.f);
      gB[4 + rg] = (_Float16)fmaxf(acc_h1[rg] + bias2[rg], 0.f);
    }

    f32x4 acc_g = MFMA16(aG2_l, gB, z);
    acc_g       = MFMA16(aG2_h, gB, acc_g);

    // epilogue: out = (agg+mb) * sigmoid(gate_pre + g2b)
#pragma unroll
    for (int rg = 0; rg < 4; ++rg) {
      const float ag = acc_a[rg] + bias0[rg];
      const float gp = acc_g[rg] + bias3[rg];
      const float gt = __builtin_amdgcn_rcpf(1.f + __expf(-gp));
      ob[(4 * q + rg) * HW + g * 16 + m] = ag * gt;
    }
  }
}

extern "C" void kernel_launch(void* const* d_in, const int* in_sizes, int n_in,
                              void* d_out, int out_size, void* d_ws, size_t ws_size,
                              hipStream_t stream) {
  // setup_inputs() order:
  // 0:x 1:qw 2:qb 3:kw 4:kb 5:mw 6:mb 7:scaling 8:g1w 9:g1b 10:g2w 11:g2b
  const float* x   = (const float*)d_in[0];
  const float* mw  = (const float*)d_in[5];
  const float* mb  = (const float*)d_in[6];
  const float* g1w = (const float*)d_in[8];
  const float* g1b = (const float*)d_in[9];
  const float* g2w = (const float*)d_in[10];
  const float* g2b = (const float*)d_in[11];
  float* out = (float*)d_out;

  // 4096 wgs x 128 thr; wave = 128 px (2 px/thread) of one image row.
  ga_main<<<4096, 128, 0, stream>>>(x, mw, mb, g1w, g1b, g2w, g2b, out);
}